// Round 12
// baseline (1146.991 us; speedup 1.0000x reference)
//
#include <hip/hip_runtime.h>
#include <hip/hip_bf16.h>
#include <math.h>

#define NNODES 100000
#define NEDGES 1600000
#define FIN 256
#define HDIM 128
#define NGRAPH 128
#define NCLS 10
#define NEG 0.2f

#define NBUCK 98            // buckets of 1024 dst nodes
#define EPB 4096            // edges per bin_place block
#define EBLK ((NEDGES + EPB - 1) / EPB)   // 391

typedef short bf8 __attribute__((ext_vector_type(8)));
typedef float f4 __attribute__((ext_vector_type(4)));

__device__ __forceinline__ float lrelu(float x) { return x > 0.f ? x : NEG * x; }

__device__ __forceinline__ unsigned short f2bf(float f) {
  union { float f; unsigned int u; } v; v.f = f;
  unsigned int r = v.u + 0x7fffu + ((v.u >> 16) & 1u);   // round-nearest-even
  return (unsigned short)(r >> 16);
}
__device__ __forceinline__ float bf2f(unsigned short u) {
  union { unsigned int u; float f; } v; v.u = ((unsigned int)u) << 16; return v.f;
}
__device__ __forceinline__ float bf_lo(unsigned int p) {
  union { unsigned int u; float f; } v; v.u = p << 16; return v.f;
}
__device__ __forceinline__ float bf_hi(unsigned int p) {
  union { unsigned int u; float f; } v; v.u = p & 0xffff0000u; return v.f;
}

// ---------------- one-shot weight convert+transpose: w[K][128] -> wt[128][K] -
__global__ __launch_bounds__(256) void convert_transpose(const float* __restrict__ w,
                                                         unsigned short* __restrict__ wt,
                                                         int K) {
  int i = blockIdx.x * 256 + threadIdx.x;
  if (i >= K * 128) return;
  int k = i >> 7, n = i & 127;
  wt[n * K + k] = f2bf(w[(size_t)k * 128 + n]);
}

// ---------------- MFMA GEMM: 64-row tiles, depth-2 register prefetch ---------
// Block tile 64 x 128 (grid ~1563 -> ~6 blocks/CU for latency hiding).
// Wave w handles m-tile w (16 rows). Two register buffers prefetch K-tiles
// k+1 and k+2, so each LDS store only waits on its own buffer's loads while
// the other buffer's loads stay in flight.
__global__ __launch_bounds__(256) void gemm_mfma(const void* __restrict__ Av,
                                                 int a_bf16,
                                                 const unsigned short* __restrict__ Bt,
                                                 const float* __restrict__ bias,
                                                 unsigned short* __restrict__ Cb,
                                                 unsigned int* __restrict__ Cp,
                                                 const float* __restrict__ a_src,
                                                 const float* __restrict__ a_dst,
                                                 float* __restrict__ o_as,
                                                 float* __restrict__ o_ad,
                                                 int M, int K, int dorelu) {
  __shared__ bf8 As[256];   // 4 m-tiles x 64 blobs
  __shared__ bf8 Bs[512];   // 8 n-tiles x 64 blobs
  int tid = threadIdx.x;
  int wv = tid >> 6, lane = tid & 63;
  int quad = lane >> 4, m16 = lane & 15;
  int row0 = blockIdx.x * 64;

  // staging coords: thread stages A blob tid (tile tid>>6) and B blobs tid, tid+256
  int l0 = tid & 63;
  int rA = row0 + (tid >> 6) * 16 + (l0 & 15); if (rA > M - 1) rA = M - 1;
  int nB0 = (tid >> 6) * 16 + (l0 & 15);
  int nB1 = (4 + (tid >> 6)) * 16 + (l0 & 15);
  int cOff = (l0 >> 4) * 8;

  float4 fA[2][2]; bf8 hA[2]; bf8 pB[2][2];
  auto loadTile = [&](int buf, int kb) {
    if (a_bf16) {
      hA[buf] = *reinterpret_cast<const bf8*>(
          (const unsigned short*)Av + (size_t)rA * K + kb + cOff);
    } else {
      const float* p = (const float*)Av + (size_t)rA * K + kb + cOff;
      fA[buf][0] = *reinterpret_cast<const float4*>(p);
      fA[buf][1] = *reinterpret_cast<const float4*>(p + 4);
    }
    pB[buf][0] = *reinterpret_cast<const bf8*>(&Bt[(size_t)nB0 * K + kb + cOff]);
    pB[buf][1] = *reinterpret_cast<const bf8*>(&Bt[(size_t)nB1 * K + kb + cOff]);
  };
  auto cvt8 = [&](float4 a, float4 b) -> bf8 {
    bf8 v;
    v[0] = (short)f2bf(a.x); v[1] = (short)f2bf(a.y);
    v[2] = (short)f2bf(a.z); v[3] = (short)f2bf(a.w);
    v[4] = (short)f2bf(b.x); v[5] = (short)f2bf(b.y);
    v[6] = (short)f2bf(b.z); v[7] = (short)f2bf(b.w);
    return v;
  };

  f4 acc[8];
#pragma unroll
  for (int b = 0; b < 8; ++b) acc[b] = (f4){0.f, 0.f, 0.f, 0.f};

  loadTile(0, 0);
  if (K > 32) loadTile(1, 32);
  int cur = 0;
  for (int kb = 0; kb < K; kb += 32) {
    __syncthreads();                    // all waves done reading LDS
    As[tid] = a_bf16 ? hA[cur] : cvt8(fA[cur][0], fA[cur][1]);
    Bs[tid] = pB[cur][0]; Bs[tid + 256] = pB[cur][1];
    __syncthreads();
    int kn = kb + 64;
    if (kn < K) loadTile(cur, kn);      // refill freed buffer, 2 tiles ahead
    bf8 af = As[wv * 64 + lane];
#pragma unroll
    for (int tn = 0; tn < 8; ++tn) {
      bf8 bfm = Bs[tn * 64 + lane];
      acc[tn] = __builtin_amdgcn_mfma_f32_16x16x32_bf16(af, bfm, acc[tn], 0, 0, 0);
    }
    cur ^= 1;
  }

  if (Cp) {
    if (a_src) {
      float aS[8], aD[8];
#pragma unroll
      for (int tn = 0; tn < 4; ++tn) {
        aS[tn]     = a_src[tn * 16 + m16];
        aS[tn + 4] = a_src[64 + tn * 16 + m16];
        aD[tn]     = a_dst[tn * 16 + m16];
        aD[tn + 4] = a_dst[64 + tn * 16 + m16];
      }
#pragma unroll
      for (int r = 0; r < 4; ++r) {
        int row = row0 + wv * 16 + quad * 4 + r;
        float ps0 = 0.f, ps1 = 0.f, pd0 = 0.f, pd1 = 0.f;
#pragma unroll
        for (int tn = 0; tn < 4; ++tn) {
          float v0 = acc[tn][r], v1 = acc[tn + 4][r];
          ps0 = fmaf(v0, aS[tn], ps0);
          ps1 = fmaf(v1, aS[tn + 4], ps1);
          pd0 = fmaf(v0, aD[tn], pd0);
          pd1 = fmaf(v1, aD[tn + 4], pd1);
        }
#pragma unroll
        for (int o = 8; o; o >>= 1) {
          ps0 += __shfl_xor(ps0, o); ps1 += __shfl_xor(ps1, o);
          pd0 += __shfl_xor(pd0, o); pd1 += __shfl_xor(pd1, o);
        }
        if (m16 == 0 && row < M) {
          o_as[2 * row] = ps0; o_as[2 * row + 1] = ps1;
          o_ad[2 * row] = pd0; o_ad[2 * row + 1] = pd1;
        }
      }
    }
#pragma unroll
    for (int tn = 0; tn < 4; ++tn)
#pragma unroll
      for (int r = 0; r < 4; ++r) {
        int row = row0 + wv * 16 + quad * 4 + r;
        if (row < M) {
          unsigned int p = (unsigned int)f2bf(acc[tn][r]) |
                           ((unsigned int)f2bf(acc[tn + 4][r]) << 16);
          Cp[(size_t)row * 64 + tn * 16 + m16] = p;
        }
      }
  } else {
#pragma unroll
    for (int tn = 0; tn < 8; ++tn) {
      float bv = bias ? bias[tn * 16 + m16] : 0.f;
#pragma unroll
      for (int r = 0; r < 4; ++r) {
        int row = row0 + wv * 16 + quad * 4 + r;
        if (row < M) {
          float v = acc[tn][r] + bv;
          if (dorelu) v = fmaxf(v, 0.f);
          Cb[(size_t)row * 128 + tn * 16 + m16] = f2bf(v);
        }
      }
    }
  }
}

// ---------------- graph boundaries (batch is sorted) -------------------------
__global__ void find_starts(const int* __restrict__ batch, int* __restrict__ gstart) {
  int g = threadIdx.x;
  if (g > NGRAPH) return;
  if (g == NGRAPH) { gstart[g] = NNODES; return; }
  int lo = 0, hi = NNODES;
  while (lo < hi) { int mid = (lo + hi) >> 1; if (batch[mid] < g) lo = mid + 1; else hi = mid; }
  gstart[g] = lo;
}

// ======== CSR build, bucketed two-phase (no random global atomics) ==========
__global__ __launch_bounds__(256) void bin_count(const int* __restrict__ edst,
                                                 int* __restrict__ blockHist) {
  __shared__ int hist[NBUCK];
  int t = threadIdx.x, blk = blockIdx.x;
  if (t < NBUCK) hist[t] = 0;
  __syncthreads();
  int e0 = blk * EPB;
#pragma unroll
  for (int it = 0; it < EPB / 256; ++it) {
    int e = e0 + it * 256 + t;
    if (e < NEDGES) atomicAdd(&hist[((unsigned)edst[e]) >> 10], 1);
  }
  __syncthreads();
  if (t < NBUCK) blockHist[blk * NBUCK + t] = hist[t];
}

__global__ __launch_bounds__(512) void colscan(const int* __restrict__ blockHist,
                                               int* __restrict__ blockBaseCol,
                                               int* __restrict__ bucket_total) {
  __shared__ int s[512];
  int b = blockIdx.x, t = threadIdx.x;
  int v = (t < EBLK) ? blockHist[t * NBUCK + b] : 0;
  s[t] = v;
  __syncthreads();
  for (int off = 1; off < 512; off <<= 1) {
    int u = (t >= off) ? s[t - off] : 0;
    __syncthreads();
    s[t] += u;
    __syncthreads();
  }
  if (t < EBLK) blockBaseCol[b * EBLK + t] = s[t] - v;
  if (t == 511) bucket_total[b] = s[511];
}

__global__ __launch_bounds__(128) void bscan(const int* __restrict__ bucket_total,
                                             int* __restrict__ bucket_ptr) {
  __shared__ int s[128];
  int t = threadIdx.x;
  int v = (t < NBUCK) ? bucket_total[t] : 0;
  s[t] = v;
  __syncthreads();
  for (int off = 1; off < 128; off <<= 1) {
    int u = (t >= off) ? s[t - off] : 0;
    __syncthreads();
    s[t] += u;
    __syncthreads();
  }
  if (t < NBUCK) bucket_ptr[t] = s[t] - v;
  if (t == 127) bucket_ptr[NBUCK] = s[127];
}

// staging entry: (dst_local_10bits << 17) | src_17bits  (NNODES < 2^17)
__global__ __launch_bounds__(512) void bin_place(const int* __restrict__ esrc,
                                                 const int* __restrict__ edst,
                                                 const int* __restrict__ blockBaseCol,
                                                 const int* __restrict__ bucket_ptr,
                                                 unsigned* __restrict__ stagingG) {
  __shared__ int hist[NBUCK + 1], lbase[NBUCK + 1], lcur[NBUCK + 1], cbase[NBUCK];
  __shared__ int tmp[128];
  __shared__ uint2 st[EPB];
  int t = threadIdx.x, blk = blockIdx.x;
  if (t < NBUCK + 1) hist[t] = 0;
  __syncthreads();
  int e0 = blk * EPB;
#pragma unroll
  for (int it = 0; it < EPB / 512; ++it) {
    int e = e0 + it * 512 + t;
    int b = NBUCK;
    if (e < NEDGES) b = ((unsigned)edst[e]) >> 10;
    atomicAdd(&hist[b], 1);
  }
  __syncthreads();
  if (t < 128) tmp[t] = (t < NBUCK + 1) ? hist[t] : 0;
  __syncthreads();
  for (int off = 1; off < 128; off <<= 1) {
    int u = 0;
    if (t < 128 && t >= off) u = tmp[t - off];
    __syncthreads();
    if (t < 128) tmp[t] += u;
    __syncthreads();
  }
  if (t < NBUCK + 1) { int ex = tmp[t] - hist[t]; lbase[t] = ex; lcur[t] = ex; }
  if (t < NBUCK) cbase[t] = bucket_ptr[t] + blockBaseCol[t * EBLK + blk];
  __syncthreads();
#pragma unroll
  for (int it = 0; it < EPB / 512; ++it) {
    int e = e0 + it * 512 + t;
    unsigned s = 0, d = 0xFFFFFFFFu;
    if (e < NEDGES) { s = (unsigned)esrc[e]; d = (unsigned)edst[e]; }
    int b = (d == 0xFFFFFFFFu) ? NBUCK : (int)(d >> 10);
    int slot = atomicAdd(&lcur[b], 1);
    st[slot] = make_uint2(s, d);
  }
  __syncthreads();
  for (int i = t; i < EPB; i += 512) {
    uint2 ed = st[i];
    if (ed.y == 0xFFFFFFFFu) continue;
    int b = (int)(ed.y >> 10);
    stagingG[cbase[b] + (i - lbase[b])] = ((ed.y & 1023u) << 17) | ed.x;
  }
}

// fused: per-bucket degree histogram + LDS scan -> row_ptr, then scatter
__global__ __launch_bounds__(1024) void bucket_csr_fused(const unsigned* __restrict__ stagingG,
                                                         const int* __restrict__ bucket_ptr,
                                                         int* __restrict__ row_ptr,
                                                         int* __restrict__ colv) {
  __shared__ int dl[1024];
  __shared__ int cur[1024];
  int b = blockIdx.x, t = threadIdx.x;
  dl[t] = 0;
  __syncthreads();
  int s0 = bucket_ptr[b], s1 = bucket_ptr[b + 1];
  for (int j = s0 + t; j < s1; j += 1024)
    atomicAdd(&dl[stagingG[j] >> 17], 1);
  __syncthreads();
  int myDeg = dl[t];
  for (int off = 1; off < 1024; off <<= 1) {
    int u = (t >= off) ? dl[t - off] : 0;
    __syncthreads();
    dl[t] += u;
    __syncthreads();
  }
  int rp = s0 + dl[t] - myDeg;
  cur[t] = rp;
  int n = (b << 10) + t;
  if (n < NNODES) row_ptr[n] = rp;
  if (n == NNODES - 1) row_ptr[NNODES] = rp + myDeg;
  __syncthreads();
  for (int j = s0 + t; j < s1; j += 1024) {
    unsigned v = stagingG[j];
    int pos = atomicAdd(&cur[v >> 17], 1);
    colv[pos] = (int)(v & 0x1FFFFu);
  }
}

// ---------------- tiered gather: compile-time lane idx -> readlane/SGPR ------
template<int T>
__device__ __forceinline__ void gather_T(const unsigned int* __restrict__ hwb,
                                         int lane, int sl, float w0l, float w1l,
                                         float& acc0, float& acc1) {
#pragma unroll
  for (int t = 0; t < T; ++t) {
    int s = __builtin_amdgcn_readlane(sl, t);                                   // SGPR
    float w0 = __uint_as_float(__builtin_amdgcn_readlane(__float_as_uint(w0l), t));
    float w1 = __uint_as_float(__builtin_amdgcn_readlane(__float_as_uint(w1l), t));
    unsigned q = hwb[(size_t)s * 64 + lane];   // saddr + lane offset
    acc0 = fmaf(w0, bf_lo(q), acc0);
    acc1 = fmaf(w1, bf_hi(q), acc1);
  }
}

// ---------------- softmax aggregation: one wave per dst node -----------------
__global__ __launch_bounds__(256) void aggregate(const unsigned int* __restrict__ hwb,
                                                 const float* __restrict__ a_s,
                                                 const float* __restrict__ a_d,
                                                 const int* __restrict__ row_ptr,
                                                 const int* __restrict__ colv,
                                                 const float* __restrict__ bias,
                                                 unsigned short* __restrict__ out) {
  int i = (blockIdx.x * 256 + threadIdx.x) >> 6;
  int lane = threadIdx.x & 63;
  if (i >= NNODES) return;
  float ad0 = a_d[2 * i], ad1 = a_d[2 * i + 1];
  float es0 = lrelu(a_s[2 * i] + ad0), es1 = lrelu(a_s[2 * i + 1] + ad1);  // self edge
  int start = row_ptr[i], end = row_ptr[i + 1];
  int deg = end - start;

  int sl = 0; float e0l = -1e30f, e1l = -1e30f;
  if (lane < deg) {
    sl = colv[start + lane];
    float2 av = *reinterpret_cast<const float2*>(&a_s[2 * sl]);
    e0l = lrelu(av.x + ad0); e1l = lrelu(av.y + ad1);
  }
  float m0 = fmaxf(es0, e0l), m1 = fmaxf(es1, e1l);
  for (int j = start + 64 + lane; j < end; j += 64) {
    int s = colv[j];
    float2 av = *reinterpret_cast<const float2*>(&a_s[2 * s]);
    m0 = fmaxf(m0, lrelu(av.x + ad0));
    m1 = fmaxf(m1, lrelu(av.y + ad1));
  }
  for (int o = 32; o; o >>= 1) {
    m0 = fmaxf(m0, __shfl_xor(m0, o));
    m1 = fmaxf(m1, __shfl_xor(m1, o));
  }
  float w0l = lane < deg ? __expf(e0l - m0) : 0.f;
  float w1l = lane < deg ? __expf(e1l - m1) : 0.f;
  float d0 = w0l, d1 = w1l;
  for (int o = 32; o; o >>= 1) { d0 += __shfl_xor(d0, o); d1 += __shfl_xor(d1, o); }
  float ws0 = __expf(es0 - m0), ws1 = __expf(es1 - m1);
  float den0 = d0 + ws0, den1 = d1 + ws1;

  unsigned int ps = hwb[(size_t)i * 64 + lane];
  float acc0 = ws0 * bf_lo(ps), acc1 = ws1 * bf_hi(ps);
  int dmin = deg < 64 ? deg : 64;
  switch ((dmin + 7) >> 3) {
    case 1: gather_T<8 >(hwb, lane, sl, w0l, w1l, acc0, acc1); break;
    case 2: gather_T<16>(hwb, lane, sl, w0l, w1l, acc0, acc1); break;
    case 3: gather_T<24>(hwb, lane, sl, w0l, w1l, acc0, acc1); break;
    case 4: gather_T<32>(hwb, lane, sl, w0l, w1l, acc0, acc1); break;
    case 5: gather_T<40>(hwb, lane, sl, w0l, w1l, acc0, acc1); break;
    case 6: gather_T<48>(hwb, lane, sl, w0l, w1l, acc0, acc1); break;
    case 7: gather_T<56>(hwb, lane, sl, w0l, w1l, acc0, acc1); break;
    case 8: gather_T<64>(hwb, lane, sl, w0l, w1l, acc0, acc1); break;
    default: break;
  }
  for (int j = start + 64; j < end; ++j) {   // rare overflow path (deg > 64)
    int s = colv[j];
    float2 av = *reinterpret_cast<const float2*>(&a_s[2 * s]);
    float w0 = __expf(lrelu(av.x + ad0) - m0);
    float w1 = __expf(lrelu(av.y + ad1) - m1);
    den0 += w0; den1 += w1;
    unsigned int q = hwb[(size_t)s * 64 + lane];
    acc0 = fmaf(w0, bf_lo(q), acc0);
    acc1 = fmaf(w1, bf_hi(q), acc1);
  }
  out[(size_t)i * 128 + lane]      = f2bf(fmaxf(acc0 / den0 + bias[lane], 0.f));
  out[(size_t)i * 128 + 64 + lane] = f2bf(fmaxf(acc1 / den1 + bias[64 + lane], 0.f));
}

// ---------------- per-graph pooling, node-parallel (bf16 input) --------------
#define SEG_CHUNK 128
__global__ __launch_bounds__(128) void seg_sum_fast(const unsigned short* __restrict__ h,
                                                    const int* __restrict__ batch,
                                                    const int* __restrict__ gstart,
                                                    float* __restrict__ reprs) {
  int n0 = blockIdx.x * SEG_CHUNK;
  if (n0 >= NNODES) return;
  int nend = n0 + SEG_CHUNK; if (nend > NNODES) nend = NNODES;
  int tid = threadIdx.x;
  int r = n0;
  while (r < nend) {
    int g = batch[r];
    int segend = gstart[g + 1]; if (segend > nend) segend = nend;
    float a0 = 0.f, a1 = 0.f, a2 = 0.f, a3 = 0.f;
    for (; r + 3 < segend; r += 4) {
      a0 += bf2f(h[(size_t)r * 128 + tid]);
      a1 += bf2f(h[(size_t)(r + 1) * 128 + tid]);
      a2 += bf2f(h[(size_t)(r + 2) * 128 + tid]);
      a3 += bf2f(h[(size_t)(r + 3) * 128 + tid]);
    }
    for (; r < segend; ++r) a0 += bf2f(h[(size_t)r * 128 + tid]);
    atomicAdd(&reprs[g * 128 + tid], (a0 + a1) + (a2 + a3));
  }
}

// ---------------- head MLP + log_softmax -------------------------------------
__global__ __launch_bounds__(128) void head_kernel(const float* __restrict__ reprs,
                                                   const float* __restrict__ pw1,
                                                   const float* __restrict__ pb1,
                                                   const float* __restrict__ pw2,
                                                   const float* __restrict__ pb2,
                                                   float* __restrict__ out) {
  __shared__ float r[128], t1[128], z[NCLS];
  int g = blockIdx.x, tid = threadIdx.x;
  r[tid] = reprs[g * 128 + tid];
  __syncthreads();
  float acc = pb1[tid];
  for (int k = 0; k < 128; ++k) acc = fmaf(r[k], pw1[k * 128 + tid], acc);
  t1[tid] = fmaxf(acc, 0.f);
  __syncthreads();
  if (tid < NCLS) {
    float zz = pb2[tid];
    for (int k = 0; k < 128; ++k) zz = fmaf(t1[k], pw2[k * NCLS + tid], zz);
    z[tid] = zz;
  }
  __syncthreads();
  if (tid == 0) {
    float mx = -1e30f;
    for (int c = 0; c < NCLS; ++c) mx = fmaxf(mx, z[c]);
    float s = 0.f;
    for (int c = 0; c < NCLS; ++c) s += expf(z[c] - mx);
    float ls = logf(s) + mx;
    for (int c = 0; c < NCLS; ++c) out[g * NCLS + c] = z[c] - ls;
  }
}

extern "C" void kernel_launch(void* const* d_in, const int* in_sizes, int n_in,
                              void* d_out, int out_size, void* d_ws, size_t ws_size,
                              hipStream_t stream) {
  const float* x     = (const float*)d_in[0];
  const int*   eidx  = (const int*)d_in[1];
  const int*   batch = (const int*)d_in[2];
  const float* pre_w = (const float*)d_in[3];
  const float* pre_b = (const float*)d_in[4];
  const float* w1    = (const float*)d_in[5];
  const float* asrc1 = (const float*)d_in[6];
  const float* adst1 = (const float*)d_in[7];
  const float* b1    = (const float*)d_in[8];
  const float* w2    = (const float*)d_in[9];
  const float* asrc2 = (const float*)d_in[10];
  const float* adst2 = (const float*)d_in[11];
  const float* b2    = (const float*)d_in[12];
  const float* pw1   = (const float*)d_in[13];
  const float* pb1   = (const float*)d_in[14];
  const float* pw2   = (const float*)d_in[15];
  const float* pb2   = (const float*)d_in[16];
  float* out = (float*)d_out;

  const int* esrc = eidx;
  const int* edst = eidx + NEDGES;

  char* wsp = (char*)d_ws;
  size_t off = 0;
  auto alloc = [&](size_t bytes) -> void* {
    void* p = wsp + off;
    off += (bytes + 255) & ~(size_t)255;
    return p;
  };
  unsigned short* hb = (unsigned short*)alloc((size_t)NNODES * 128 * 2);
  unsigned int* hwb  = (unsigned int*)alloc((size_t)NNODES * 64 * 4);
  float* a_s         = (float*)alloc((size_t)NNODES * 2 * 4);
  float* a_d         = (float*)alloc((size_t)NNODES * 2 * 4);
  float* reprs       = (float*)alloc((size_t)NGRAPH * 128 * 4);
  int* gstart        = (int*)alloc((NGRAPH + 1) * 4);
  int* row_ptr       = (int*)alloc(((size_t)NNODES + 1) * 4);
  int* colv          = (int*)alloc((size_t)NEDGES * 4);
  unsigned short* wt_pre = (unsigned short*)alloc((size_t)128 * FIN * 2);
  unsigned short* wt1    = (unsigned short*)alloc((size_t)128 * HDIM * 2);
  unsigned short* wt2    = (unsigned short*)alloc((size_t)128 * HDIM * 2);
  int* blockHist     = (int*)alloc((size_t)EBLK * NBUCK * 4);
  int* blockBaseCol  = (int*)alloc((size_t)NBUCK * EBLK * 4);
  int* bucket_total  = (int*)alloc(NBUCK * 4);
  int* bucket_ptr    = (int*)alloc((NBUCK + 1) * 4);
  unsigned* stagingG = (unsigned*)alloc((size_t)NEDGES * 4);

  int wb = NNODES / 4;             // wave-per-node kernels: 256 thr = 4 waves
  int sb = (NNODES + SEG_CHUNK - 1) / SEG_CHUNK;
  int gb = (NNODES + 63) / 64;     // 1563 GEMM blocks (64-row tiles)

  // one-shot weight conversion (bf16, transposed)
  convert_transpose<<<(FIN * 128 + 255) / 256, 256, 0, stream>>>(pre_w, wt_pre, FIN);
  convert_transpose<<<(HDIM * 128 + 255) / 256, 256, 0, stream>>>(w1, wt1, HDIM);
  convert_transpose<<<(HDIM * 128 + 255) / 256, 256, 0, stream>>>(w2, wt2, HDIM);

  // graph boundaries + zeroed pooling accumulator
  hipMemsetAsync(reprs, 0, (size_t)NGRAPH * 128 * 4, stream);
  find_starts<<<1, 256, 0, stream>>>(batch, gstart);

  // bucketed CSR build (packed 4B staging; fused deg-scan + scatter)
  bin_count<<<EBLK, 256, 0, stream>>>(edst, blockHist);
  colscan<<<NBUCK, 512, 0, stream>>>(blockHist, blockBaseCol, bucket_total);
  bscan<<<1, 128, 0, stream>>>(bucket_total, bucket_ptr);
  bin_place<<<EBLK, 512, 0, stream>>>(esrc, edst, blockBaseCol, bucket_ptr, stagingG);
  bucket_csr_fused<<<NBUCK, 1024, 0, stream>>>(stagingG, bucket_ptr, row_ptr, colv);

  // pre layer: h0 = relu(x @ pre_w + pre_b)  (bf16 h)
  gemm_mfma<<<gb, 256, 0, stream>>>(x, 0, wt_pre, pre_b, hb, nullptr,
                                    nullptr, nullptr, nullptr, nullptr, NNODES, FIN, 1);
  seg_sum_fast<<<sb, 128, 0, stream>>>(hb, batch, gstart, reprs);

  // GAT layer 1 (bf16 A; alpha fused into GEMM epilogue)
  gemm_mfma<<<gb, 256, 0, stream>>>(hb, 1, wt1, nullptr, nullptr, hwb,
                                    asrc1, adst1, a_s, a_d, NNODES, HDIM, 0);
  aggregate<<<wb, 256, 0, stream>>>(hwb, a_s, a_d, row_ptr, colv, b1, hb);
  seg_sum_fast<<<sb, 128, 0, stream>>>(hb, batch, gstart, reprs);

  // GAT layer 2
  gemm_mfma<<<gb, 256, 0, stream>>>(hb, 1, wt2, nullptr, nullptr, hwb,
                                    asrc2, adst2, a_s, a_d, NNODES, HDIM, 0);
  aggregate<<<wb, 256, 0, stream>>>(hwb, a_s, a_d, row_ptr, colv, b2, hb);
  seg_sum_fast<<<sb, 128, 0, stream>>>(hb, batch, gstart, reprs);

  // head
  head_kernel<<<NGRAPH, 128, 0, stream>>>(reprs, pw1, pb1, pw2, pb2, out);
}

// Round 13
// 495.800 us; speedup vs baseline: 2.3134x; 2.3134x over previous
//
#include <hip/hip_runtime.h>
#include <hip/hip_bf16.h>
#include <math.h>

#define NNODES 100000
#define NEDGES 1600000
#define FIN 256
#define HDIM 128
#define NGRAPH 128
#define NCLS 10
#define NEG 0.2f

#define NBUCK 98            // buckets of 1024 dst nodes
#define EPB 4096            // edges per bin_place block
#define EBLK ((NEDGES + EPB - 1) / EPB)   // 391

typedef short bf8 __attribute__((ext_vector_type(8)));
typedef float f4 __attribute__((ext_vector_type(4)));

__device__ __forceinline__ float lrelu(float x) { return x > 0.f ? x : NEG * x; }

__device__ __forceinline__ unsigned short f2bf(float f) {
  union { float f; unsigned int u; } v; v.f = f;
  unsigned int r = v.u + 0x7fffu + ((v.u >> 16) & 1u);   // round-nearest-even
  return (unsigned short)(r >> 16);
}
__device__ __forceinline__ float bf2f(unsigned short u) {
  union { unsigned int u; float f; } v; v.u = ((unsigned int)u) << 16; return v.f;
}
__device__ __forceinline__ float bf_lo(unsigned int p) {
  union { unsigned int u; float f; } v; v.u = p << 16; return v.f;
}
__device__ __forceinline__ float bf_hi(unsigned int p) {
  union { unsigned int u; float f; } v; v.u = p & 0xffff0000u; return v.f;
}

// ---------------- one-shot weight convert+transpose: w[K][128] -> wt[128][K] -
__global__ __launch_bounds__(256) void convert_transpose(const float* __restrict__ w,
                                                         unsigned short* __restrict__ wt,
                                                         int K) {
  int i = blockIdx.x * 256 + threadIdx.x;
  if (i >= K * 128) return;
  int k = i >> 7, n = i & 127;
  wt[n * K + k] = f2bf(w[(size_t)k * 128 + n]);
}

// ---------------- MFMA GEMM: 64-row tiles, depth-2 prefetch (STATIC buffers) -
// Block tile 64 x 128 (grid ~1563 -> ~6 blocks/CU). Wave w: m-tile w (16 rows).
// K-loop unrolled x2 so buffer selection is compile-time (runtime-indexed
// register arrays spill to scratch -- R11 lesson: 110MB scratch writes).
__global__ __launch_bounds__(256) void gemm_mfma(const void* __restrict__ Av,
                                                 int a_bf16,
                                                 const unsigned short* __restrict__ Bt,
                                                 const float* __restrict__ bias,
                                                 unsigned short* __restrict__ Cb,
                                                 unsigned int* __restrict__ Cp,
                                                 const float* __restrict__ a_src,
                                                 const float* __restrict__ a_dst,
                                                 float* __restrict__ o_as,
                                                 float* __restrict__ o_ad,
                                                 int M, int K, int dorelu) {
  __shared__ bf8 As[256];   // 4 m-tiles x 64 blobs
  __shared__ bf8 Bs[512];   // 8 n-tiles x 64 blobs
  int tid = threadIdx.x;
  int wv = tid >> 6, lane = tid & 63;
  int quad = lane >> 4, m16 = lane & 15;
  int row0 = blockIdx.x * 64;

  int l0 = tid & 63;
  int rA = row0 + (tid >> 6) * 16 + (l0 & 15); if (rA > M - 1) rA = M - 1;
  int nB0 = (tid >> 6) * 16 + (l0 & 15);
  int nB1 = (4 + (tid >> 6)) * 16 + (l0 & 15);
  int cOff = (l0 >> 4) * 8;

  // buffer 0 / buffer 1: named scalars only (no runtime indexing!)
  float4 f0a, f0b, f1a, f1b;
  bf8 h0, h1, b00, b01, b10, b11;

  auto loadT0 = [&](int kb) {
    if (a_bf16) {
      h0 = *reinterpret_cast<const bf8*>((const unsigned short*)Av + (size_t)rA * K + kb + cOff);
    } else {
      const float* p = (const float*)Av + (size_t)rA * K + kb + cOff;
      f0a = *reinterpret_cast<const float4*>(p);
      f0b = *reinterpret_cast<const float4*>(p + 4);
    }
    b00 = *reinterpret_cast<const bf8*>(&Bt[(size_t)nB0 * K + kb + cOff]);
    b01 = *reinterpret_cast<const bf8*>(&Bt[(size_t)nB1 * K + kb + cOff]);
  };
  auto loadT1 = [&](int kb) {
    if (a_bf16) {
      h1 = *reinterpret_cast<const bf8*>((const unsigned short*)Av + (size_t)rA * K + kb + cOff);
    } else {
      const float* p = (const float*)Av + (size_t)rA * K + kb + cOff;
      f1a = *reinterpret_cast<const float4*>(p);
      f1b = *reinterpret_cast<const float4*>(p + 4);
    }
    b10 = *reinterpret_cast<const bf8*>(&Bt[(size_t)nB0 * K + kb + cOff]);
    b11 = *reinterpret_cast<const bf8*>(&Bt[(size_t)nB1 * K + kb + cOff]);
  };
  auto cvt8 = [&](float4 a, float4 b) -> bf8 {
    bf8 v;
    v[0] = (short)f2bf(a.x); v[1] = (short)f2bf(a.y);
    v[2] = (short)f2bf(a.z); v[3] = (short)f2bf(a.w);
    v[4] = (short)f2bf(b.x); v[5] = (short)f2bf(b.y);
    v[6] = (short)f2bf(b.z); v[7] = (short)f2bf(b.w);
    return v;
  };

  f4 acc[8];
#pragma unroll
  for (int b = 0; b < 8; ++b) acc[b] = (f4){0.f, 0.f, 0.f, 0.f};

  loadT0(0);
  loadT1(32);               // K is always >= 64 and a multiple of 64
  for (int kb = 0; kb < K; kb += 64) {
    // ---- step A: consume buffer 0 (tile kb) ----
    __syncthreads();
    As[tid] = a_bf16 ? h0 : cvt8(f0a, f0b);
    Bs[tid] = b00; Bs[tid + 256] = b01;
    __syncthreads();
    if (kb + 64 < K) loadT0(kb + 64);
    {
      bf8 af = As[wv * 64 + lane];
#pragma unroll
      for (int tn = 0; tn < 8; ++tn) {
        bf8 bfm = Bs[tn * 64 + lane];
        acc[tn] = __builtin_amdgcn_mfma_f32_16x16x32_bf16(af, bfm, acc[tn], 0, 0, 0);
      }
    }
    // ---- step B: consume buffer 1 (tile kb+32) ----
    __syncthreads();
    As[tid] = a_bf16 ? h1 : cvt8(f1a, f1b);
    Bs[tid] = b10; Bs[tid + 256] = b11;
    __syncthreads();
    if (kb + 96 < K) loadT1(kb + 96);
    {
      bf8 af = As[wv * 64 + lane];
#pragma unroll
      for (int tn = 0; tn < 8; ++tn) {
        bf8 bfm = Bs[tn * 64 + lane];
        acc[tn] = __builtin_amdgcn_mfma_f32_16x16x32_bf16(af, bfm, acc[tn], 0, 0, 0);
      }
    }
  }

  if (Cp) {
    if (a_src) {
      float aS[8], aD[8];
#pragma unroll
      for (int tn = 0; tn < 4; ++tn) {
        aS[tn]     = a_src[tn * 16 + m16];
        aS[tn + 4] = a_src[64 + tn * 16 + m16];
        aD[tn]     = a_dst[tn * 16 + m16];
        aD[tn + 4] = a_dst[64 + tn * 16 + m16];
      }
#pragma unroll
      for (int r = 0; r < 4; ++r) {
        int row = row0 + wv * 16 + quad * 4 + r;
        float ps0 = 0.f, ps1 = 0.f, pd0 = 0.f, pd1 = 0.f;
#pragma unroll
        for (int tn = 0; tn < 4; ++tn) {
          float v0 = acc[tn][r], v1 = acc[tn + 4][r];
          ps0 = fmaf(v0, aS[tn], ps0);
          ps1 = fmaf(v1, aS[tn + 4], ps1);
          pd0 = fmaf(v0, aD[tn], pd0);
          pd1 = fmaf(v1, aD[tn + 4], pd1);
        }
#pragma unroll
        for (int o = 8; o; o >>= 1) {
          ps0 += __shfl_xor(ps0, o); ps1 += __shfl_xor(ps1, o);
          pd0 += __shfl_xor(pd0, o); pd1 += __shfl_xor(pd1, o);
        }
        if (m16 == 0 && row < M) {
          o_as[2 * row] = ps0; o_as[2 * row + 1] = ps1;
          o_ad[2 * row] = pd0; o_ad[2 * row + 1] = pd1;
        }
      }
    }
#pragma unroll
    for (int tn = 0; tn < 4; ++tn)
#pragma unroll
      for (int r = 0; r < 4; ++r) {
        int row = row0 + wv * 16 + quad * 4 + r;
        if (row < M) {
          unsigned int p = (unsigned int)f2bf(acc[tn][r]) |
                           ((unsigned int)f2bf(acc[tn + 4][r]) << 16);
          Cp[(size_t)row * 64 + tn * 16 + m16] = p;
        }
      }
  } else {
#pragma unroll
    for (int tn = 0; tn < 8; ++tn) {
      float bv = bias ? bias[tn * 16 + m16] : 0.f;
#pragma unroll
      for (int r = 0; r < 4; ++r) {
        int row = row0 + wv * 16 + quad * 4 + r;
        if (row < M) {
          float v = acc[tn][r] + bv;
          if (dorelu) v = fmaxf(v, 0.f);
          Cb[(size_t)row * 128 + tn * 16 + m16] = f2bf(v);
        }
      }
    }
  }
}

// ---------------- graph boundaries (batch is sorted) -------------------------
__global__ void find_starts(const int* __restrict__ batch, int* __restrict__ gstart) {
  int g = threadIdx.x;
  if (g > NGRAPH) return;
  if (g == NGRAPH) { gstart[g] = NNODES; return; }
  int lo = 0, hi = NNODES;
  while (lo < hi) { int mid = (lo + hi) >> 1; if (batch[mid] < g) lo = mid + 1; else hi = mid; }
  gstart[g] = lo;
}

// ======== CSR build, bucketed two-phase (no random global atomics) ==========
__global__ __launch_bounds__(256) void bin_count(const int* __restrict__ edst,
                                                 int* __restrict__ blockHist) {
  __shared__ int hist[NBUCK];
  int t = threadIdx.x, blk = blockIdx.x;
  if (t < NBUCK) hist[t] = 0;
  __syncthreads();
  int e0 = blk * EPB;
#pragma unroll
  for (int it = 0; it < EPB / 256; ++it) {
    int e = e0 + it * 256 + t;
    if (e < NEDGES) atomicAdd(&hist[((unsigned)edst[e]) >> 10], 1);
  }
  __syncthreads();
  if (t < NBUCK) blockHist[blk * NBUCK + t] = hist[t];
}

__global__ __launch_bounds__(512) void colscan(const int* __restrict__ blockHist,
                                               int* __restrict__ blockBaseCol,
                                               int* __restrict__ bucket_total) {
  __shared__ int s[512];
  int b = blockIdx.x, t = threadIdx.x;
  int v = (t < EBLK) ? blockHist[t * NBUCK + b] : 0;
  s[t] = v;
  __syncthreads();
  for (int off = 1; off < 512; off <<= 1) {
    int u = (t >= off) ? s[t - off] : 0;
    __syncthreads();
    s[t] += u;
    __syncthreads();
  }
  if (t < EBLK) blockBaseCol[b * EBLK + t] = s[t] - v;
  if (t == 511) bucket_total[b] = s[511];
}

__global__ __launch_bounds__(128) void bscan(const int* __restrict__ bucket_total,
                                             int* __restrict__ bucket_ptr) {
  __shared__ int s[128];
  int t = threadIdx.x;
  int v = (t < NBUCK) ? bucket_total[t] : 0;
  s[t] = v;
  __syncthreads();
  for (int off = 1; off < 128; off <<= 1) {
    int u = (t >= off) ? s[t - off] : 0;
    __syncthreads();
    s[t] += u;
    __syncthreads();
  }
  if (t < NBUCK) bucket_ptr[t] = s[t] - v;
  if (t == 127) bucket_ptr[NBUCK] = s[127];
}

// staging entry: (dst_local_10bits << 17) | src_17bits  (NNODES < 2^17)
__global__ __launch_bounds__(512) void bin_place(const int* __restrict__ esrc,
                                                 const int* __restrict__ edst,
                                                 const int* __restrict__ blockBaseCol,
                                                 const int* __restrict__ bucket_ptr,
                                                 unsigned* __restrict__ stagingG) {
  __shared__ int hist[NBUCK + 1], lbase[NBUCK + 1], lcur[NBUCK + 1], cbase[NBUCK];
  __shared__ int tmp[128];
  __shared__ uint2 st[EPB];
  int t = threadIdx.x, blk = blockIdx.x;
  if (t < NBUCK + 1) hist[t] = 0;
  __syncthreads();
  int e0 = blk * EPB;
#pragma unroll
  for (int it = 0; it < EPB / 512; ++it) {
    int e = e0 + it * 512 + t;
    int b = NBUCK;
    if (e < NEDGES) b = ((unsigned)edst[e]) >> 10;
    atomicAdd(&hist[b], 1);
  }
  __syncthreads();
  if (t < 128) tmp[t] = (t < NBUCK + 1) ? hist[t] : 0;
  __syncthreads();
  for (int off = 1; off < 128; off <<= 1) {
    int u = 0;
    if (t < 128 && t >= off) u = tmp[t - off];
    __syncthreads();
    if (t < 128) tmp[t] += u;
    __syncthreads();
  }
  if (t < NBUCK + 1) { int ex = tmp[t] - hist[t]; lbase[t] = ex; lcur[t] = ex; }
  if (t < NBUCK) cbase[t] = bucket_ptr[t] + blockBaseCol[t * EBLK + blk];
  __syncthreads();
#pragma unroll
  for (int it = 0; it < EPB / 512; ++it) {
    int e = e0 + it * 512 + t;
    unsigned s = 0, d = 0xFFFFFFFFu;
    if (e < NEDGES) { s = (unsigned)esrc[e]; d = (unsigned)edst[e]; }
    int b = (d == 0xFFFFFFFFu) ? NBUCK : (int)(d >> 10);
    int slot = atomicAdd(&lcur[b], 1);
    st[slot] = make_uint2(s, d);
  }
  __syncthreads();
  for (int i = t; i < EPB; i += 512) {
    uint2 ed = st[i];
    if (ed.y == 0xFFFFFFFFu) continue;
    int b = (int)(ed.y >> 10);
    stagingG[cbase[b] + (i - lbase[b])] = ((ed.y & 1023u) << 17) | ed.x;
  }
}

// fused: per-bucket degree histogram + LDS scan -> row_ptr, then scatter
__global__ __launch_bounds__(1024) void bucket_csr_fused(const unsigned* __restrict__ stagingG,
                                                         const int* __restrict__ bucket_ptr,
                                                         int* __restrict__ row_ptr,
                                                         int* __restrict__ colv) {
  __shared__ int dl[1024];
  __shared__ int cur[1024];
  int b = blockIdx.x, t = threadIdx.x;
  dl[t] = 0;
  __syncthreads();
  int s0 = bucket_ptr[b], s1 = bucket_ptr[b + 1];
  for (int j = s0 + t; j < s1; j += 1024)
    atomicAdd(&dl[stagingG[j] >> 17], 1);
  __syncthreads();
  int myDeg = dl[t];
  for (int off = 1; off < 1024; off <<= 1) {
    int u = (t >= off) ? dl[t - off] : 0;
    __syncthreads();
    dl[t] += u;
    __syncthreads();
  }
  int rp = s0 + dl[t] - myDeg;
  cur[t] = rp;
  int n = (b << 10) + t;
  if (n < NNODES) row_ptr[n] = rp;
  if (n == NNODES - 1) row_ptr[NNODES] = rp + myDeg;
  __syncthreads();
  for (int j = s0 + t; j < s1; j += 1024) {
    unsigned v = stagingG[j];
    int pos = atomicAdd(&cur[v >> 17], 1);
    colv[pos] = (int)(v & 0x1FFFFu);
  }
}

// ---------------- tiered gather: compile-time lane idx -> readlane/SGPR ------
template<int T>
__device__ __forceinline__ void gather_T(const unsigned int* __restrict__ hwb,
                                         int lane, int sl, float w0l, float w1l,
                                         float& acc0, float& acc1) {
#pragma unroll
  for (int t = 0; t < T; ++t) {
    int s = __builtin_amdgcn_readlane(sl, t);                                   // SGPR
    float w0 = __uint_as_float(__builtin_amdgcn_readlane(__float_as_uint(w0l), t));
    float w1 = __uint_as_float(__builtin_amdgcn_readlane(__float_as_uint(w1l), t));
    unsigned q = hwb[(size_t)s * 64 + lane];   // saddr + lane offset
    acc0 = fmaf(w0, bf_lo(q), acc0);
    acc1 = fmaf(w1, bf_hi(q), acc1);
  }
}

// ---------------- softmax aggregation: one wave per dst node -----------------
__global__ __launch_bounds__(256) void aggregate(const unsigned int* __restrict__ hwb,
                                                 const float* __restrict__ a_s,
                                                 const float* __restrict__ a_d,
                                                 const int* __restrict__ row_ptr,
                                                 const int* __restrict__ colv,
                                                 const float* __restrict__ bias,
                                                 unsigned short* __restrict__ out) {
  int i = (blockIdx.x * 256 + threadIdx.x) >> 6;
  int lane = threadIdx.x & 63;
  if (i >= NNODES) return;
  float ad0 = a_d[2 * i], ad1 = a_d[2 * i + 1];
  float es0 = lrelu(a_s[2 * i] + ad0), es1 = lrelu(a_s[2 * i + 1] + ad1);  // self edge
  int start = row_ptr[i], end = row_ptr[i + 1];
  int deg = end - start;

  int sl = 0; float e0l = -1e30f, e1l = -1e30f;
  if (lane < deg) {
    sl = colv[start + lane];
    float2 av = *reinterpret_cast<const float2*>(&a_s[2 * sl]);
    e0l = lrelu(av.x + ad0); e1l = lrelu(av.y + ad1);
  }
  float m0 = fmaxf(es0, e0l), m1 = fmaxf(es1, e1l);
  for (int j = start + 64 + lane; j < end; j += 64) {
    int s = colv[j];
    float2 av = *reinterpret_cast<const float2*>(&a_s[2 * s]);
    m0 = fmaxf(m0, lrelu(av.x + ad0));
    m1 = fmaxf(m1, lrelu(av.y + ad1));
  }
  for (int o = 32; o; o >>= 1) {
    m0 = fmaxf(m0, __shfl_xor(m0, o));
    m1 = fmaxf(m1, __shfl_xor(m1, o));
  }
  float w0l = lane < deg ? __expf(e0l - m0) : 0.f;
  float w1l = lane < deg ? __expf(e1l - m1) : 0.f;
  float d0 = w0l, d1 = w1l;
  for (int o = 32; o; o >>= 1) { d0 += __shfl_xor(d0, o); d1 += __shfl_xor(d1, o); }
  float ws0 = __expf(es0 - m0), ws1 = __expf(es1 - m1);
  float den0 = d0 + ws0, den1 = d1 + ws1;

  unsigned int ps = hwb[(size_t)i * 64 + lane];
  float acc0 = ws0 * bf_lo(ps), acc1 = ws1 * bf_hi(ps);
  int dmin = deg < 64 ? deg : 64;
  switch ((dmin + 7) >> 3) {
    case 1: gather_T<8 >(hwb, lane, sl, w0l, w1l, acc0, acc1); break;
    case 2: gather_T<16>(hwb, lane, sl, w0l, w1l, acc0, acc1); break;
    case 3: gather_T<24>(hwb, lane, sl, w0l, w1l, acc0, acc1); break;
    case 4: gather_T<32>(hwb, lane, sl, w0l, w1l, acc0, acc1); break;
    case 5: gather_T<40>(hwb, lane, sl, w0l, w1l, acc0, acc1); break;
    case 6: gather_T<48>(hwb, lane, sl, w0l, w1l, acc0, acc1); break;
    case 7: gather_T<56>(hwb, lane, sl, w0l, w1l, acc0, acc1); break;
    case 8: gather_T<64>(hwb, lane, sl, w0l, w1l, acc0, acc1); break;
    default: break;
  }
  for (int j = start + 64; j < end; ++j) {   // rare overflow path (deg > 64)
    int s = colv[j];
    float2 av = *reinterpret_cast<const float2*>(&a_s[2 * s]);
    float w0 = __expf(lrelu(av.x + ad0) - m0);
    float w1 = __expf(lrelu(av.y + ad1) - m1);
    den0 += w0; den1 += w1;
    unsigned int q = hwb[(size_t)s * 64 + lane];
    acc0 = fmaf(w0, bf_lo(q), acc0);
    acc1 = fmaf(w1, bf_hi(q), acc1);
  }
  out[(size_t)i * 128 + lane]      = f2bf(fmaxf(acc0 / den0 + bias[lane], 0.f));
  out[(size_t)i * 128 + 64 + lane] = f2bf(fmaxf(acc1 / den1 + bias[64 + lane], 0.f));
}

// ---------------- per-graph pooling, node-parallel (bf16 input) --------------
#define SEG_CHUNK 128
__global__ __launch_bounds__(128) void seg_sum_fast(const unsigned short* __restrict__ h,
                                                    const int* __restrict__ batch,
                                                    const int* __restrict__ gstart,
                                                    float* __restrict__ reprs) {
  int n0 = blockIdx.x * SEG_CHUNK;
  if (n0 >= NNODES) return;
  int nend = n0 + SEG_CHUNK; if (nend > NNODES) nend = NNODES;
  int tid = threadIdx.x;
  int r = n0;
  while (r < nend) {
    int g = batch[r];
    int segend = gstart[g + 1]; if (segend > nend) segend = nend;
    float a0 = 0.f, a1 = 0.f, a2 = 0.f, a3 = 0.f;
    for (; r + 3 < segend; r += 4) {
      a0 += bf2f(h[(size_t)r * 128 + tid]);
      a1 += bf2f(h[(size_t)(r + 1) * 128 + tid]);
      a2 += bf2f(h[(size_t)(r + 2) * 128 + tid]);
      a3 += bf2f(h[(size_t)(r + 3) * 128 + tid]);
    }
    for (; r < segend; ++r) a0 += bf2f(h[(size_t)r * 128 + tid]);
    atomicAdd(&reprs[g * 128 + tid], (a0 + a1) + (a2 + a3));
  }
}

// ---------------- head MLP + log_softmax -------------------------------------
__global__ __launch_bounds__(128) void head_kernel(const float* __restrict__ reprs,
                                                   const float* __restrict__ pw1,
                                                   const float* __restrict__ pb1,
                                                   const float* __restrict__ pw2,
                                                   const float* __restrict__ pb2,
                                                   float* __restrict__ out) {
  __shared__ float r[128], t1[128], z[NCLS];
  int g = blockIdx.x, tid = threadIdx.x;
  r[tid] = reprs[g * 128 + tid];
  __syncthreads();
  float acc = pb1[tid];
  for (int k = 0; k < 128; ++k) acc = fmaf(r[k], pw1[k * 128 + tid], acc);
  t1[tid] = fmaxf(acc, 0.f);
  __syncthreads();
  if (tid < NCLS) {
    float zz = pb2[tid];
    for (int k = 0; k < 128; ++k) zz = fmaf(t1[k], pw2[k * NCLS + tid], zz);
    z[tid] = zz;
  }
  __syncthreads();
  if (tid == 0) {
    float mx = -1e30f;
    for (int c = 0; c < NCLS; ++c) mx = fmaxf(mx, z[c]);
    float s = 0.f;
    for (int c = 0; c < NCLS; ++c) s += expf(z[c] - mx);
    float ls = logf(s) + mx;
    for (int c = 0; c < NCLS; ++c) out[g * NCLS + c] = z[c] - ls;
  }
}

extern "C" void kernel_launch(void* const* d_in, const int* in_sizes, int n_in,
                              void* d_out, int out_size, void* d_ws, size_t ws_size,
                              hipStream_t stream) {
  const float* x     = (const float*)d_in[0];
  const int*   eidx  = (const int*)d_in[1];
  const int*   batch = (const int*)d_in[2];
  const float* pre_w = (const float*)d_in[3];
  const float* pre_b = (const float*)d_in[4];
  const float* w1    = (const float*)d_in[5];
  const float* asrc1 = (const float*)d_in[6];
  const float* adst1 = (const float*)d_in[7];
  const float* b1    = (const float*)d_in[8];
  const float* w2    = (const float*)d_in[9];
  const float* asrc2 = (const float*)d_in[10];
  const float* adst2 = (const float*)d_in[11];
  const float* b2    = (const float*)d_in[12];
  const float* pw1   = (const float*)d_in[13];
  const float* pb1   = (const float*)d_in[14];
  const float* pw2   = (const float*)d_in[15];
  const float* pb2   = (const float*)d_in[16];
  float* out = (float*)d_out;

  const int* esrc = eidx;
  const int* edst = eidx + NEDGES;

  char* wsp = (char*)d_ws;
  size_t off = 0;
  auto alloc = [&](size_t bytes) -> void* {
    void* p = wsp + off;
    off += (bytes + 255) & ~(size_t)255;
    return p;
  };
  unsigned short* hb = (unsigned short*)alloc((size_t)NNODES * 128 * 2);
  unsigned int* hwb  = (unsigned int*)alloc((size_t)NNODES * 64 * 4);
  float* a_s         = (float*)alloc((size_t)NNODES * 2 * 4);
  float* a_d         = (float*)alloc((size_t)NNODES * 2 * 4);
  float* reprs       = (float*)alloc((size_t)NGRAPH * 128 * 4);
  int* gstart        = (int*)alloc((NGRAPH + 1) * 4);
  int* row_ptr       = (int*)alloc(((size_t)NNODES + 1) * 4);
  int* colv          = (int*)alloc((size_t)NEDGES * 4);
  unsigned short* wt_pre = (unsigned short*)alloc((size_t)128 * FIN * 2);
  unsigned short* wt1    = (unsigned short*)alloc((size_t)128 * HDIM * 2);
  unsigned short* wt2    = (unsigned short*)alloc((size_t)128 * HDIM * 2);
  int* blockHist     = (int*)alloc((size_t)EBLK * NBUCK * 4);
  int* blockBaseCol  = (int*)alloc((size_t)NBUCK * EBLK * 4);
  int* bucket_total  = (int*)alloc(NBUCK * 4);
  int* bucket_ptr    = (int*)alloc((NBUCK + 1) * 4);
  unsigned* stagingG = (unsigned*)alloc((size_t)NEDGES * 4);

  int wb = NNODES / 4;             // wave-per-node kernels: 256 thr = 4 waves
  int sb = (NNODES + SEG_CHUNK - 1) / SEG_CHUNK;
  int gb = (NNODES + 63) / 64;     // 1563 GEMM blocks (64-row tiles)

  // one-shot weight conversion (bf16, transposed)
  convert_transpose<<<(FIN * 128 + 255) / 256, 256, 0, stream>>>(pre_w, wt_pre, FIN);
  convert_transpose<<<(HDIM * 128 + 255) / 256, 256, 0, stream>>>(w1, wt1, HDIM);
  convert_transpose<<<(HDIM * 128 + 255) / 256, 256, 0, stream>>>(w2, wt2, HDIM);

  // graph boundaries + zeroed pooling accumulator
  hipMemsetAsync(reprs, 0, (size_t)NGRAPH * 128 * 4, stream);
  find_starts<<<1, 256, 0, stream>>>(batch, gstart);

  // bucketed CSR build (packed 4B staging; fused deg-scan + scatter)
  bin_count<<<EBLK, 256, 0, stream>>>(edst, blockHist);
  colscan<<<NBUCK, 512, 0, stream>>>(blockHist, blockBaseCol, bucket_total);
  bscan<<<1, 128, 0, stream>>>(bucket_total, bucket_ptr);
  bin_place<<<EBLK, 512, 0, stream>>>(esrc, edst, blockBaseCol, bucket_ptr, stagingG);
  bucket_csr_fused<<<NBUCK, 1024, 0, stream>>>(stagingG, bucket_ptr, row_ptr, colv);

  // pre layer: h0 = relu(x @ pre_w + pre_b)  (bf16 h)
  gemm_mfma<<<gb, 256, 0, stream>>>(x, 0, wt_pre, pre_b, hb, nullptr,
                                    nullptr, nullptr, nullptr, nullptr, NNODES, FIN, 1);
  seg_sum_fast<<<sb, 128, 0, stream>>>(hb, batch, gstart, reprs);

  // GAT layer 1 (bf16 A; alpha fused into GEMM epilogue)
  gemm_mfma<<<gb, 256, 0, stream>>>(hb, 1, wt1, nullptr, nullptr, hwb,
                                    asrc1, adst1, a_s, a_d, NNODES, HDIM, 0);
  aggregate<<<wb, 256, 0, stream>>>(hwb, a_s, a_d, row_ptr, colv, b1, hb);
  seg_sum_fast<<<sb, 128, 0, stream>>>(hb, batch, gstart, reprs);

  // GAT layer 2
  gemm_mfma<<<gb, 256, 0, stream>>>(hb, 1, wt2, nullptr, nullptr, hwb,
                                    asrc2, adst2, a_s, a_d, NNODES, HDIM, 0);
  aggregate<<<wb, 256, 0, stream>>>(hwb, a_s, a_d, row_ptr, colv, b2, hb);
  seg_sum_fast<<<sb, 128, 0, stream>>>(hb, batch, gstart, reprs);

  // head
  head_kernel<<<NGRAPH, 128, 0, stream>>>(reprs, pw1, pb1, pw2, pb2, out);
}